// Round 12
// baseline (2539.166 us; speedup 1.0000x reference)
//
#include <hip/hip_runtime.h>
#include <math.h>

#define NODE 5
#define TT 512
#define NBATCH 8192
#define NB 16            // batch elems per block
#define MR (NB*NODE)     // 80 rows (row80 = node*16 + e)
#define TB 32
#define XS_DIM 325
#define H2 256
#define EPS 1e-5f

typedef _Float16 h16;
typedef __attribute__((ext_vector_type(8))) _Float16 half8;
typedef __attribute__((ext_vector_type(4))) _Float16 h16x4;
typedef __attribute__((ext_vector_type(2))) _Float16 half2v;
typedef __attribute__((ext_vector_type(4))) float float4v;

// Swizzle recap (unchanged since round 5): half-index hi = row*LDW +
// (hc ^ ((row&7)<<3)). Every accessed row = k*16 + ln, so row&7 == ln&7:
// the XOR is a PER-LANE CONSTANT -> all LDS addresses = per-thread base +
// compile-time byte offset (nd*4096 / nd*2048 / +20480 for GD[1]).
__device__ __forceinline__ float rfl_f(float v) {
    return __uint_as_float(__builtin_amdgcn_readfirstlane(__float_as_uint(v)));
}
// v_cvt_pkrtz_f16_f32: 1 instr packs 2 f32 -> 2 f16 (RTZ; mix inputs only).
__device__ __forceinline__ half2v pkrtz(float a, float b) {
    return __builtin_bit_cast(half2v, __builtin_amdgcn_cvt_pkrtz(a, b));
}
__device__ __forceinline__ half2v pkmax0(half2v v) {
    half2v z; z[0] = (h16)0.f; z[1] = (h16)0.f;
    return __builtin_elementwise_max(v, z);
}

// ---------------------------------------------------------------------------
// RNN kernel, 256 threads (4 waves), row80 = node*16 + e (node-major),
// fused-mix structure (3 barriers/step). Round-12 delta: adjacency entries
// are EXACTLY {0.0, 1.0} (bernoulli), wave-uniform, in SGPRs. The node-mix
// g[i] += A[i][nd]*p is therefore a SCALAR-GUARDED PACKED-ADD:
//   fma(1,p,g) == g+p and fma(0,p,g) == g  (bit-identical, p finite)
// -> skip zero terms via uniform s_cbranch (free SALU pipe), expected ~50%
// of the 250 mix fma/step eliminated; ahp f16 adjacency regs removed.
// Also: a2 zero-init hoisted out of the nd loop (only slot 0 changes).
// Bit-identical to round 11's math. Other parts unchanged:
//  - x rank-1 folded into MFMA K-dim (wf0x/a2, bias as C-in)
//  - tanh: med3 clamp + v_exp_f32 + rcp, th = fma(-2, rc, 1)
//  - setprio(1) around MFMA clusters; L3 VALU tail at prio 0
// __launch_bounds__(256,2) => 128-VGPR cap (empirical: rounds 0-1, 5-11).
// ---------------------------------------------------------------------------
__global__ __launch_bounds__(256, 2) void rnn_kernel(
    const float* __restrict__ x, const float* __restrict__ adj,
    const float* __restrict__ W0, const float* __restrict__ b0,
    const float* __restrict__ W1, const float* __restrict__ b1,
    const float* __restrict__ W2, const float* __restrict__ b2,
    float* __restrict__ xs)
{
    __shared__ __align__(16) h16 sGD[2][MR*128]; // 40960 B (L1 out / L2 out)
    __shared__ __align__(16) h16 sGS[MR*64];     // 10240 B (state, mixed)
    __shared__ h16  sx[2][TB][NODE][16];         // 10240 B (x chunks, dbuf)
    __shared__ h16  sxg[TB][MR];                 //  5120 B (mixed x, f16)

    const int tid  = threadIdx.x;
    const int lane = tid & 63;
    const int w    = tid >> 6;       // wave 0..3
    const int ln   = lane & 15;      // col = batch elem e
    const int q    = lane >> 4;      // quad 0..3
    const int k0q  = q*8;
    const int bbase = blockIdx.x * NB;

    // ---- persistent LDS byte-bases (see swizzle recap above) ----
    char* const gd0 = (char*)&sGD[0][0];
    char* const gsB = (char*)&sGS[0];
    const int xorv = (ln & 7) << 3;
    const int rB0 = ln*256 + 2*(( 0 + k0q) ^ xorv);  // GD read, ks even (ks>=2: +128)
    const int rB1 = ln*256 + 2*((32 + k0q) ^ xorv);  // GD read, ks odd
    const int gR0 = ln*128 + 2*(( 0 + k0q) ^ xorv);  // GS read, a0
    const int gR1 = ln*128 + 2*((32 + k0q) ^ xorv);  // GS read, a1
    const int wB0 = ln*256 + 2*(((2*w+0)*16 + q*4) ^ xorv);  // GD write t2=0
    const int wB1 = ln*256 + 2*(((2*w+1)*16 + q*4) ^ xorv);  // GD write t2=1
    const int gW  = ln*128 + 2*((w*16 + q*4) ^ xorv);        // GS write

    // ---- A = adj.T, wave-uniform -> SGPRs: f32 (sxg pass) + 0/1 masks ----
    float af[NODE][NODE];
    bool  az[NODE][NODE];
    #pragma unroll
    for (int i = 0; i < NODE; ++i)
        #pragma unroll
        for (int j = 0; j < NODE; ++j) {
            float v = rfl_f(adj[j*NODE + i]);
            af[i][j] = v;
            az[i][j] = (v != 0.f);
        }

    // ---- weight fragments (VGPRs): two 16-feat tiles per wave (L1/L2),
    //      one (L3). A-frag of W^T: lane holds W[ks*32+q*8+j][feat tile]. ----
    half8 wf0[2][2], wf0x[2], wf1f[2][4], wf3[4];
    {
        #pragma unroll
        for (int t2 = 0; t2 < 2; ++t2) {
            int n1 = (2*w+t2)*16 + ln;
            #pragma unroll
            for (int ks = 0; ks < 2; ++ks) {
                half8 f;
                #pragma unroll
                for (int j = 0; j < 8; ++j)
                    f[j] = (h16)W0[(size_t)(1 + ks*32 + k0q + j)*128 + n1]; // rows 1..64
                wf0[t2][ks] = f;
            }
            // x-block A-frag: k-slot 64 (q==0, j==0) = W0 row 0, else 0
            {
                half8 f;
                #pragma unroll
                for (int j = 0; j < 8; ++j) f[j] = (h16)0.f;
                if (q == 0) f[0] = (h16)W0[n1];
                wf0x[t2] = f;
            }
            #pragma unroll
            for (int ks = 0; ks < 4; ++ks) {
                half8 f;
                #pragma unroll
                for (int j = 0; j < 8; ++j)
                    f[j] = (h16)W1[(size_t)(ks*32 + k0q + j)*128 + n1];
                wf1f[t2][ks] = f;
            }
        }
        int n3 = w*16 + ln;
        #pragma unroll
        for (int ks = 0; ks < 4; ++ks) {
            half8 f;
            #pragma unroll
            for (int j = 0; j < 8; ++j)
                f[j] = (h16)W2[(size_t)(ks*32 + k0q + j)*64 + n3];
            wf3[ks] = f;
        }
    }
    // Bias quads (MFMA C-operand init), per out-feature.
    float4v b0q[2], b1q[2], b2q;
    #pragma unroll
    for (int t2 = 0; t2 < 2; ++t2)
        #pragma unroll
        for (int r = 0; r < 4; ++r) {
            int fi = (2*w+t2)*16 + q*4 + r;
            b0q[t2][r] = b0[fi];
            b1q[t2][r] = b1[fi];
        }
    #pragma unroll
    for (int r = 0; r < 4; ++r) b2q[r] = b2[w*16 + q*4 + r];

    // ---- prologue: stage x chunk 0, zero initial mixed state ----
    for (int i = tid; i < TB*NODE*16; i += 256) {
        int tl = i & 31; int ne = i >> 5; int n = ne >> 4; int e = ne & 15;
        sx[0][tl][n][e] = (h16)x[((size_t)(bbase+e)*NODE + n)*TT + tl];
    }
    for (int i = tid; i < MR*64; i += 256) sGS[i] = (h16)0.f;
    __syncthreads();

    #pragma unroll 1
    for (int tc = 0; tc < TT/TB; ++tc) {
        const int buf = tc & 1;
        // mixed x for this chunk (f16): sxg[ti][nd*16+e] = sum_j af[nd][j]*x
        for (int i = tid; i < TB*MR; i += 256) {
            int ti = i / MR, row = i - ti*MR;
            int nd = row >> 4, e = row & 15;
            float acc = 0.f;
            #pragma unroll
            for (int j = 0; j < NODE; ++j)
                acc += af[nd][j] * (float)sx[buf][ti][j][e];
            sxg[ti][row] = (h16)acc;
        }
        if (tc+1 < TT/TB) {   // stage next chunk (other buffer)
            for (int i = tid; i < TB*NODE*16; i += 256) {
                int tl = i & 31; int ne = i >> 5; int n = ne >> 4; int e = ne & 15;
                sx[buf^1][tl][n][e] =
                    (h16)x[((size_t)(bbase+e)*NODE + n)*TT + (tc+1)*TB + tl];
            }
        }
        __syncthreads();

        #pragma unroll 1
        for (int tt = 0; tt < TB; ++tt) {
            const int t = tc*TB + tt;
            // -------- L1 + mix: G1 = A @ relu([x|gS] W0 + b0) -------------
            {
                half2v g[2][NODE][2];
                #pragma unroll
                for (int t2 = 0; t2 < 2; ++t2)
                    #pragma unroll
                    for (int i = 0; i < NODE; ++i) {
                        half2v z; z[0] = (h16)0.f; z[1] = (h16)0.f;
                        g[t2][i][0] = z; g[t2][i][1] = z;
                    }
                half8 a2;     // x k-block B-frag: only slot 0 varies per nd
                #pragma unroll
                for (int j = 0; j < 8; ++j) a2[j] = (h16)0.f;
                __builtin_amdgcn_s_setprio(1);
                #pragma unroll
                for (int nd = 0; nd < NODE; ++nd) {
                    half8 a0 = *(const half8*)(gsB + gR0 + nd*2048);
                    half8 a1 = *(const half8*)(gsB + gR1 + nd*2048);
                    h16 xgv = sxg[tt][nd*16 + ln];
                    a2[0] = (q == 0) ? xgv : (h16)0.f;
                    half2v p[2][2];
                    #pragma unroll
                    for (int t2 = 0; t2 < 2; ++t2) {
                        float4v acc = __builtin_amdgcn_mfma_f32_16x16x32_f16(wf0x[t2], a2, b0q[t2], 0,0,0);
                        acc = __builtin_amdgcn_mfma_f32_16x16x32_f16(wf0[t2][0], a0, acc, 0,0,0);
                        acc = __builtin_amdgcn_mfma_f32_16x16x32_f16(wf0[t2][1], a1, acc, 0,0,0);
                        p[t2][0] = pkmax0(pkrtz(acc[0], acc[1]));
                        p[t2][1] = pkmax0(pkrtz(acc[2], acc[3]));
                    }
                    #pragma unroll
                    for (int i = 0; i < NODE; ++i)
                        if (az[i][nd]) {   // A entry == 1: masked packed-add
                            g[0][i][0] += p[0][0]; g[0][i][1] += p[0][1];
                            g[1][i][0] += p[1][0]; g[1][i][1] += p[1][1];
                        }
                }
                __builtin_amdgcn_s_setprio(0);
                #pragma unroll
                for (int t2 = 0; t2 < 2; ++t2)
                    #pragma unroll
                    for (int i = 0; i < NODE; ++i) {
                        h16x4 o;
                        o[0]=g[t2][i][0][0]; o[1]=g[t2][i][0][1];
                        o[2]=g[t2][i][1][0]; o[3]=g[t2][i][1][1];
                        *(h16x4*)(gd0 + (t2 ? wB1 : wB0) + i*4096) = o;
                    }
            }
            __syncthreads();
            // -------- L2 + mix: G2 = A @ relu(G1 W1 + b1) -----------------
            {
                half2v g[2][NODE][2];
                #pragma unroll
                for (int t2 = 0; t2 < 2; ++t2)
                    #pragma unroll
                    for (int i = 0; i < NODE; ++i) {
                        half2v z; z[0] = (h16)0.f; z[1] = (h16)0.f;
                        g[t2][i][0] = z; g[t2][i][1] = z;
                    }
                __builtin_amdgcn_s_setprio(1);
                #pragma unroll
                for (int nd = 0; nd < NODE; ++nd) {
                    half8 a[4];
                    a[0] = *(const half8*)(gd0 + rB0 +       nd*4096);
                    a[1] = *(const half8*)(gd0 + rB1 +       nd*4096);
                    a[2] = *(const half8*)(gd0 + rB0 + 128 + nd*4096);
                    a[3] = *(const half8*)(gd0 + rB1 + 128 + nd*4096);
                    half2v p[2][2];
                    #pragma unroll
                    for (int t2 = 0; t2 < 2; ++t2) {
                        float4v acc = __builtin_amdgcn_mfma_f32_16x16x32_f16(wf1f[t2][0], a[0], b1q[t2], 0,0,0);
                        #pragma unroll
                        for (int ks = 1; ks < 4; ++ks)
                            acc = __builtin_amdgcn_mfma_f32_16x16x32_f16(wf1f[t2][ks], a[ks], acc, 0,0,0);
                        p[t2][0] = pkmax0(pkrtz(acc[0], acc[1]));
                        p[t2][1] = pkmax0(pkrtz(acc[2], acc[3]));
                    }
                    #pragma unroll
                    for (int i = 0; i < NODE; ++i)
                        if (az[i][nd]) {
                            g[0][i][0] += p[0][0]; g[0][i][1] += p[0][1];
                            g[1][i][0] += p[1][0]; g[1][i][1] += p[1][1];
                        }
                }
                __builtin_amdgcn_s_setprio(0);
                #pragma unroll
                for (int t2 = 0; t2 < 2; ++t2)
                    #pragma unroll
                    for (int i = 0; i < NODE; ++i) {
                        h16x4 o;
                        o[0]=g[t2][i][0][0]; o[1]=g[t2][i][0][1];
                        o[2]=g[t2][i][1][0]; o[3]=g[t2][i][1][1];
                        *(h16x4*)(gd0 + 20480 + (t2 ? wB1 : wB0) + i*4096) = o;
                    }
            }
            __syncthreads();
            // -------- L3 + mix: state = tanh(G2 W2 + b2); GS = A @ state --
            {
                const bool last = (t == TT-1);
                half2v gp[NODE][2];
                #pragma unroll
                for (int i = 0; i < NODE; ++i) {
                    half2v z; z[0] = (h16)0.f; z[1] = (h16)0.f;
                    gp[i][0] = z; gp[i][1] = z;
                }
                #pragma unroll
                for (int nd = 0; nd < NODE; ++nd) {
                    half8 a[4];
                    a[0] = *(const half8*)(gd0 + 20480 + rB0 +       nd*4096);
                    a[1] = *(const half8*)(gd0 + 20480 + rB1 +       nd*4096);
                    a[2] = *(const half8*)(gd0 + 20480 + rB0 + 128 + nd*4096);
                    a[3] = *(const half8*)(gd0 + 20480 + rB1 + 128 + nd*4096);
                    __builtin_amdgcn_s_setprio(1);
                    float4v acc = __builtin_amdgcn_mfma_f32_16x16x32_f16(wf3[0], a[0], b2q, 0,0,0);
                    #pragma unroll
                    for (int ks = 1; ks < 4; ++ks)
                        acc = __builtin_amdgcn_mfma_f32_16x16x32_f16(wf3[ks], a[ks], acc, 0,0,0);
                    __builtin_amdgcn_s_setprio(0);
                    float th[4];
                    #pragma unroll
                    for (int r = 0; r < 4; ++r) {
                        // tanh(z) = 1 - 2/(E+1), E = 2^(2*log2e*clamp(z,±9))
                        float zc = __builtin_amdgcn_fmed3f(acc[r], -9.f, 9.f);
                        float E  = __builtin_amdgcn_exp2f(zc * 2.885390082f);
                        float rc = __builtin_amdgcn_rcpf(E + 1.f);
                        th[r] = fmaf(-2.f, rc, 1.f);
                    }
                    if (last) {   // raw state straight to xs (once, exact f32)
                        size_t ob = (size_t)(bbase+ln)*XS_DIM + 5 + nd*64 + w*16 + q*4;
                        #pragma unroll
                        for (int r = 0; r < 4; ++r) xs[ob + r] = th[r];
                    }
                    half2v p0 = pkrtz(th[0], th[1]);
                    half2v p1 = pkrtz(th[2], th[3]);
                    #pragma unroll
                    for (int i = 0; i < NODE; ++i)
                        if (az[i][nd]) {
                            gp[i][0] += p0;
                            gp[i][1] += p1;
                        }
                }
                #pragma unroll
                for (int i = 0; i < NODE; ++i) {
                    h16x4 o;
                    o[0]=gp[i][0][0]; o[1]=gp[i][0][1];
                    o[2]=gp[i][1][0]; o[3]=gp[i][1][1];
                    *(h16x4*)(gsB + gW + i*2048) = o;
                }
            }
            __syncthreads();
        }
    }

    // ---- epilogue: x_end -> xs[b][0..4] ----
    if (tid < NB*NODE) {
        int e = tid / NODE, j = tid - (tid/NODE)*NODE;
        xs[(size_t)(bbase+e)*XS_DIM + j] = (float)sx[1][TB-1][j][e];   // t=511
    }
}

// ---------------------------------------------------------------------------
// Kernel B: h = relu(xs @ fc1_w + fc1_b) + per-column sum/sumsq for BN.
// ---------------------------------------------------------------------------
__global__ __launch_bounds__(256) void fc1_kernel(
    const float* __restrict__ xs, const float* __restrict__ fc1_w,
    const float* __restrict__ fc1_b, float* __restrict__ h,
    float* __restrict__ sums)
{
    __shared__ float s_xs[16*XS_DIM];
    const int tid = threadIdx.x;
    const int r0 = blockIdx.x * 16;
    for (int i = tid; i < 16*XS_DIM; i += 256)
        s_xs[i] = xs[(size_t)r0*XS_DIM + i];
    __syncthreads();

    float acc[16];
    #pragma unroll
    for (int r = 0; r < 16; ++r) acc[r] = 0.f;
    for (int k = 0; k < XS_DIM; ++k) {
        float wv = fc1_w[(size_t)k*H2 + tid];
        #pragma unroll
        for (int r = 0; r < 16; ++r) acc[r] += s_xs[r*XS_DIM + k]*wv;
    }
    float bb = fc1_b[tid];
    float ls = 0.f, lq = 0.f;
    #pragma unroll
    for (int r = 0; r < 16; ++r) {
        float v = fmaxf(acc[r] + bb, 0.f);
        h[(size_t)(r0+r)*H2 + tid] = v;
        ls += v; lq += v*v;
    }
    atomicAdd(&sums[tid], ls);
    atomicAdd(&sums[H2 + tid], lq);
}

// ---------------------------------------------------------------------------
// Kernel C: BN(train) normalize + fc2 + softmax. One wave per row.
// ---------------------------------------------------------------------------
__global__ __launch_bounds__(256) void head_kernel(
    const float* __restrict__ h, const float* __restrict__ sums,
    const float* __restrict__ gamma, const float* __restrict__ beta,
    const float* __restrict__ fc2_w, const float* __restrict__ fc2_b,
    float* __restrict__ out)
{
    const int lane = threadIdx.x & 63;
    const int r = blockIdx.x*4 + (threadIdx.x >> 6);
    const int c0 = lane*4;

    float4 hv = *(const float4*)&h[(size_t)r*H2 + c0];
    float hvv[4] = {hv.x, hv.y, hv.z, hv.w};
    float y[4];
    #pragma unroll
    for (int c = 0; c < 4; ++c) {
        int cc = c0 + c;
        float mean = sums[cc] * (1.f/NBATCH);
        float var  = sums[H2+cc]*(1.f/NBATCH) - mean*mean;
        float rstd = rsqrtf(var + EPS);
        y[c] = (hvv[c] - mean)*rstd*gamma[cc] + beta[cc];
    }
    float lg[7];
    #pragma unroll
    for (int j = 0; j < 7; ++j) {
        float p = 0.f;
        #pragma unroll
        for (int c = 0; c < 4; ++c) p += y[c]*fc2_w[(size_t)(c0+c)*7 + j];
        #pragma unroll
        for (int off = 32; off >= 1; off >>= 1) p += __shfl_xor(p, off, 64);
        lg[j] = p + fc2_b[j];
    }
    if (lane == 0) {
        float m = lg[0];
        #pragma unroll
        for (int j = 1; j < 7; ++j) m = fmaxf(m, lg[j]);
        float ev[7]; float s = 0.f;
        #pragma unroll
        for (int j = 0; j < 7; ++j) { ev[j] = expf(lg[j]-m); s += ev[j]; }
        float inv = 1.f/s;
        #pragma unroll
        for (int j = 0; j < 7; ++j) out[(size_t)r*7 + j] = ev[j]*inv;
    }
}

// ---------------------------------------------------------------------------
extern "C" void kernel_launch(void* const* d_in, const int* in_sizes, int n_in,
                              void* d_out, int out_size, void* d_ws, size_t ws_size,
                              hipStream_t stream)
{
    (void)in_sizes; (void)n_in; (void)out_size; (void)ws_size;
    const float* x     = (const float*)d_in[0];
    const float* adj   = (const float*)d_in[1];
    const float* W0    = (const float*)d_in[2];
    const float* b0    = (const float*)d_in[3];
    const float* W1    = (const float*)d_in[4];
    const float* b1    = (const float*)d_in[5];
    const float* W2    = (const float*)d_in[6];
    const float* b2    = (const float*)d_in[7];
    const float* fc1w  = (const float*)d_in[8];
    const float* fc1b  = (const float*)d_in[9];
    const float* gamma = (const float*)d_in[10];
    const float* beta  = (const float*)d_in[11];
    const float* fc2w  = (const float*)d_in[12];
    const float* fc2b  = (const float*)d_in[13];
    float* out = (float*)d_out;

    char* ws = (char*)d_ws;
    float* xs   = (float*)(ws);                                  // 8192*325 f32
    float* hbuf = (float*)(ws + 10649600);                       // 8192*256 f32
    float* sums = (float*)(ws + 10649600 + 8388608);             // 512 f32

    hipMemsetAsync(sums, 0, 512*sizeof(float), stream);
    rnn_kernel<<<NBATCH/NB, 256, 0, stream>>>(x, adj, W0, b0, W1, b1, W2, b2, xs);
    fc1_kernel<<<NBATCH/16, 256, 0, stream>>>(xs, fc1w, fc1b, hbuf, sums);
    head_kernel<<<NBATCH/4, 256, 0, stream>>>(hbuf, sums, gamma, beta, fc2w, fc2b, out);
}

// Round 13
// 2186.774 us; speedup vs baseline: 1.1611x; 1.1611x over previous
//
#include <hip/hip_runtime.h>
#include <math.h>

#define NODE 5
#define TT 512
#define NBATCH 8192
#define NB 16            // batch elems per block
#define MR (NB*NODE)     // 80 rows (row80 = node*16 + e)
#define TB 32
#define XS_DIM 325
#define H2 256
#define EPS 1e-5f

typedef _Float16 h16;
typedef __attribute__((ext_vector_type(8))) _Float16 half8;
typedef __attribute__((ext_vector_type(4))) _Float16 h16x4;
typedef __attribute__((ext_vector_type(2))) _Float16 half2v;
typedef __attribute__((ext_vector_type(4))) float float4v;

// Swizzle recap (unchanged since round 5): half-index hi = row*LDW +
// (hc ^ ((row&7)<<3)). Every accessed row = k*16 + ln, so row&7 == ln&7:
// the XOR is a PER-LANE CONSTANT -> all LDS addresses = per-thread base +
// compile-time byte offset (nd*4096 / nd*2048 / +20480 for GD[1]).
__device__ __forceinline__ float rfl_f(float v) {
    return __uint_as_float(__builtin_amdgcn_readfirstlane(__float_as_uint(v)));
}
// v_cvt_pkrtz_f16_f32: 1 instr packs 2 f32 -> 2 f16 (RTZ; mix inputs only).
__device__ __forceinline__ half2v pkrtz(float a, float b) {
    return __builtin_bit_cast(half2v, __builtin_amdgcn_cvt_pkrtz(a, b));
}
__device__ __forceinline__ half2v pkmax0(half2v v) {
    half2v z; z[0] = (h16)0.f; z[1] = (h16)0.f;
    return __builtin_elementwise_max(v, z);
}

// ---------------------------------------------------------------------------
// RNN kernel, 256 threads (4 waves), row80 = node*16 + e (node-major),
// fused-mix structure (3 barriers/step). Round-13 = REVERT to round-11 (best:
// 2190 µs). Round-12's uniform-branch mask-skip REGRESSED 15%: s_cbranch
// edges fragmented the unrolled schedule (ILP loss > VALU-count gain) —
// unconditional v_pk_fma mixes schedule better. Final configuration:
//  - fused in-register node-mix, 3 barriers/step (r4/r5 quadrant sweep)
//  - 4 waves, 2 blocks/CU; LDS base+imm addressing (r7)
//  - x rank-1 folded into MFMA K-dim (wf0x/a2, bias as C-in) (r9)
//  - pkrtz/pk_max f16 epilogues + packed-f16 mixes (r6/r10)
//  - tanh: med3 clamp + v_exp_f32 + rcp, th = fma(-2, rc, 1) (r9/r10)
//  - setprio(1) around MFMA clusters (r9)
// __launch_bounds__(256,2) => 128-VGPR cap (empirical: rounds 0-1, 5-11).
// ---------------------------------------------------------------------------
__global__ __launch_bounds__(256, 2) void rnn_kernel(
    const float* __restrict__ x, const float* __restrict__ adj,
    const float* __restrict__ W0, const float* __restrict__ b0,
    const float* __restrict__ W1, const float* __restrict__ b1,
    const float* __restrict__ W2, const float* __restrict__ b2,
    float* __restrict__ xs)
{
    __shared__ __align__(16) h16 sGD[2][MR*128]; // 40960 B (L1 out / L2 out)
    __shared__ __align__(16) h16 sGS[MR*64];     // 10240 B (state, mixed)
    __shared__ h16  sx[2][TB][NODE][16];         // 10240 B (x chunks, dbuf)
    __shared__ h16  sxg[TB][MR];                 //  5120 B (mixed x, f16)

    const int tid  = threadIdx.x;
    const int lane = tid & 63;
    const int w    = tid >> 6;       // wave 0..3
    const int ln   = lane & 15;      // col = batch elem e
    const int q    = lane >> 4;      // quad 0..3
    const int k0q  = q*8;
    const int bbase = blockIdx.x * NB;

    // ---- persistent LDS byte-bases (see swizzle recap above) ----
    char* const gd0 = (char*)&sGD[0][0];
    char* const gsB = (char*)&sGS[0];
    const int xorv = (ln & 7) << 3;
    const int rB0 = ln*256 + 2*(( 0 + k0q) ^ xorv);  // GD read, ks even (ks>=2: +128)
    const int rB1 = ln*256 + 2*((32 + k0q) ^ xorv);  // GD read, ks odd
    const int gR0 = ln*128 + 2*(( 0 + k0q) ^ xorv);  // GS read, a0
    const int gR1 = ln*128 + 2*((32 + k0q) ^ xorv);  // GS read, a1
    const int wB0 = ln*256 + 2*(((2*w+0)*16 + q*4) ^ xorv);  // GD write t2=0
    const int wB1 = ln*256 + 2*(((2*w+1)*16 + q*4) ^ xorv);  // GD write t2=1
    const int gW  = ln*128 + 2*((w*16 + q*4) ^ xorv);        // GS write

    // ---- A = adj.T, wave-uniform -> SGPRs (f32 + packed f16 copies) ----
    float  af[NODE][NODE];
    half2v ahp[NODE][NODE];
    #pragma unroll
    for (int i = 0; i < NODE; ++i)
        #pragma unroll
        for (int j = 0; j < NODE; ++j) {
            float v = rfl_f(adj[j*NODE + i]);
            af[i][j] = v;
            h16 hv = (h16)v;
            half2v t; t[0] = hv; t[1] = hv;
            ahp[i][j] = t;
        }

    // ---- weight fragments (VGPRs): two 16-feat tiles per wave (L1/L2),
    //      one (L3). A-frag of W^T: lane holds W[ks*32+q*8+j][feat tile]. ----
    half8 wf0[2][2], wf0x[2], wf1f[2][4], wf3[4];
    {
        #pragma unroll
        for (int t2 = 0; t2 < 2; ++t2) {
            int n1 = (2*w+t2)*16 + ln;
            #pragma unroll
            for (int ks = 0; ks < 2; ++ks) {
                half8 f;
                #pragma unroll
                for (int j = 0; j < 8; ++j)
                    f[j] = (h16)W0[(size_t)(1 + ks*32 + k0q + j)*128 + n1]; // rows 1..64
                wf0[t2][ks] = f;
            }
            // x-block A-frag: k-slot 64 (q==0, j==0) = W0 row 0, else 0
            {
                half8 f;
                #pragma unroll
                for (int j = 0; j < 8; ++j) f[j] = (h16)0.f;
                if (q == 0) f[0] = (h16)W0[n1];
                wf0x[t2] = f;
            }
            #pragma unroll
            for (int ks = 0; ks < 4; ++ks) {
                half8 f;
                #pragma unroll
                for (int j = 0; j < 8; ++j)
                    f[j] = (h16)W1[(size_t)(ks*32 + k0q + j)*128 + n1];
                wf1f[t2][ks] = f;
            }
        }
        int n3 = w*16 + ln;
        #pragma unroll
        for (int ks = 0; ks < 4; ++ks) {
            half8 f;
            #pragma unroll
            for (int j = 0; j < 8; ++j)
                f[j] = (h16)W2[(size_t)(ks*32 + k0q + j)*64 + n3];
            wf3[ks] = f;
        }
    }
    // Bias quads (MFMA C-operand init), per out-feature.
    float4v b0q[2], b1q[2], b2q;
    #pragma unroll
    for (int t2 = 0; t2 < 2; ++t2)
        #pragma unroll
        for (int r = 0; r < 4; ++r) {
            int fi = (2*w+t2)*16 + q*4 + r;
            b0q[t2][r] = b0[fi];
            b1q[t2][r] = b1[fi];
        }
    #pragma unroll
    for (int r = 0; r < 4; ++r) b2q[r] = b2[w*16 + q*4 + r];

    // ---- prologue: stage x chunk 0, zero initial mixed state ----
    for (int i = tid; i < TB*NODE*16; i += 256) {
        int tl = i & 31; int ne = i >> 5; int n = ne >> 4; int e = ne & 15;
        sx[0][tl][n][e] = (h16)x[((size_t)(bbase+e)*NODE + n)*TT + tl];
    }
    for (int i = tid; i < MR*64; i += 256) sGS[i] = (h16)0.f;
    __syncthreads();

    #pragma unroll 1
    for (int tc = 0; tc < TT/TB; ++tc) {
        const int buf = tc & 1;
        // mixed x for this chunk (f16): sxg[ti][nd*16+e] = sum_j af[nd][j]*x
        for (int i = tid; i < TB*MR; i += 256) {
            int ti = i / MR, row = i - ti*MR;
            int nd = row >> 4, e = row & 15;
            float acc = 0.f;
            #pragma unroll
            for (int j = 0; j < NODE; ++j)
                acc += af[nd][j] * (float)sx[buf][ti][j][e];
            sxg[ti][row] = (h16)acc;
        }
        if (tc+1 < TT/TB) {   // stage next chunk (other buffer)
            for (int i = tid; i < TB*NODE*16; i += 256) {
                int tl = i & 31; int ne = i >> 5; int n = ne >> 4; int e = ne & 15;
                sx[buf^1][tl][n][e] =
                    (h16)x[((size_t)(bbase+e)*NODE + n)*TT + (tc+1)*TB + tl];
            }
        }
        __syncthreads();

        #pragma unroll 1
        for (int tt = 0; tt < TB; ++tt) {
            const int t = tc*TB + tt;
            // -------- L1 + mix: G1 = A @ relu([x|gS] W0 + b0) -------------
            {
                half2v g[2][NODE][2];
                __builtin_amdgcn_s_setprio(1);
                #pragma unroll
                for (int nd = 0; nd < NODE; ++nd) {
                    half8 a0 = *(const half8*)(gsB + gR0 + nd*2048);
                    half8 a1 = *(const half8*)(gsB + gR1 + nd*2048);
                    // B-frag for the x k-block: slot 64 (q==0,j==0) = xg
                    h16 xgv = sxg[tt][nd*16 + ln];
                    half8 a2;
                    #pragma unroll
                    for (int j = 0; j < 8; ++j) a2[j] = (h16)0.f;
                    if (q == 0) a2[0] = xgv;
                    #pragma unroll
                    for (int t2 = 0; t2 < 2; ++t2) {
                        float4v acc = __builtin_amdgcn_mfma_f32_16x16x32_f16(wf0x[t2], a2, b0q[t2], 0,0,0);
                        acc = __builtin_amdgcn_mfma_f32_16x16x32_f16(wf0[t2][0], a0, acc, 0,0,0);
                        acc = __builtin_amdgcn_mfma_f32_16x16x32_f16(wf0[t2][1], a1, acc, 0,0,0);
                        half2v p0 = pkmax0(pkrtz(acc[0], acc[1]));
                        half2v p1 = pkmax0(pkrtz(acc[2], acc[3]));
                        if (nd == 0) {
                            #pragma unroll
                            for (int i = 0; i < NODE; ++i) {
                                g[t2][i][0] = ahp[i][0]*p0;
                                g[t2][i][1] = ahp[i][0]*p1;
                            }
                        } else {
                            #pragma unroll
                            for (int i = 0; i < NODE; ++i) {
                                g[t2][i][0] += ahp[i][nd]*p0;
                                g[t2][i][1] += ahp[i][nd]*p1;
                            }
                        }
                    }
                }
                __builtin_amdgcn_s_setprio(0);
                #pragma unroll
                for (int t2 = 0; t2 < 2; ++t2)
                    #pragma unroll
                    for (int i = 0; i < NODE; ++i) {
                        h16x4 o;
                        o[0]=g[t2][i][0][0]; o[1]=g[t2][i][0][1];
                        o[2]=g[t2][i][1][0]; o[3]=g[t2][i][1][1];
                        *(h16x4*)(gd0 + (t2 ? wB1 : wB0) + i*4096) = o;
                    }
            }
            __syncthreads();
            // -------- L2 + mix: G2 = A @ relu(G1 W1 + b1) -----------------
            {
                half2v g[2][NODE][2];
                __builtin_amdgcn_s_setprio(1);
                #pragma unroll
                for (int nd = 0; nd < NODE; ++nd) {
                    half8 a[4];
                    a[0] = *(const half8*)(gd0 + rB0 +       nd*4096);
                    a[1] = *(const half8*)(gd0 + rB1 +       nd*4096);
                    a[2] = *(const half8*)(gd0 + rB0 + 128 + nd*4096);
                    a[3] = *(const half8*)(gd0 + rB1 + 128 + nd*4096);
                    #pragma unroll
                    for (int t2 = 0; t2 < 2; ++t2) {
                        float4v acc = __builtin_amdgcn_mfma_f32_16x16x32_f16(wf1f[t2][0], a[0], b1q[t2], 0,0,0);
                        #pragma unroll
                        for (int ks = 1; ks < 4; ++ks)
                            acc = __builtin_amdgcn_mfma_f32_16x16x32_f16(wf1f[t2][ks], a[ks], acc, 0,0,0);
                        half2v p0 = pkmax0(pkrtz(acc[0], acc[1]));
                        half2v p1 = pkmax0(pkrtz(acc[2], acc[3]));
                        if (nd == 0) {
                            #pragma unroll
                            for (int i = 0; i < NODE; ++i) {
                                g[t2][i][0] = ahp[i][0]*p0;
                                g[t2][i][1] = ahp[i][0]*p1;
                            }
                        } else {
                            #pragma unroll
                            for (int i = 0; i < NODE; ++i) {
                                g[t2][i][0] += ahp[i][nd]*p0;
                                g[t2][i][1] += ahp[i][nd]*p1;
                            }
                        }
                    }
                }
                __builtin_amdgcn_s_setprio(0);
                #pragma unroll
                for (int t2 = 0; t2 < 2; ++t2)
                    #pragma unroll
                    for (int i = 0; i < NODE; ++i) {
                        h16x4 o;
                        o[0]=g[t2][i][0][0]; o[1]=g[t2][i][0][1];
                        o[2]=g[t2][i][1][0]; o[3]=g[t2][i][1][1];
                        *(h16x4*)(gd0 + 20480 + (t2 ? wB1 : wB0) + i*4096) = o;
                    }
            }
            __syncthreads();
            // -------- L3 + mix: state = tanh(G2 W2 + b2); GS = A @ state --
            {
                const bool last = (t == TT-1);
                half2v gp[NODE][2];
                #pragma unroll
                for (int nd = 0; nd < NODE; ++nd) {
                    half8 a[4];
                    a[0] = *(const half8*)(gd0 + 20480 + rB0 +       nd*4096);
                    a[1] = *(const half8*)(gd0 + 20480 + rB1 +       nd*4096);
                    a[2] = *(const half8*)(gd0 + 20480 + rB0 + 128 + nd*4096);
                    a[3] = *(const half8*)(gd0 + 20480 + rB1 + 128 + nd*4096);
                    __builtin_amdgcn_s_setprio(1);
                    float4v acc = __builtin_amdgcn_mfma_f32_16x16x32_f16(wf3[0], a[0], b2q, 0,0,0);
                    #pragma unroll
                    for (int ks = 1; ks < 4; ++ks)
                        acc = __builtin_amdgcn_mfma_f32_16x16x32_f16(wf3[ks], a[ks], acc, 0,0,0);
                    __builtin_amdgcn_s_setprio(0);
                    float th[4];
                    #pragma unroll
                    for (int r = 0; r < 4; ++r) {
                        // tanh(z) = 1 - 2/(E+1), E = 2^(2*log2e*clamp(z,±9))
                        float zc = __builtin_amdgcn_fmed3f(acc[r], -9.f, 9.f);
                        float E  = __builtin_amdgcn_exp2f(zc * 2.885390082f);
                        float rc = __builtin_amdgcn_rcpf(E + 1.f);
                        th[r] = fmaf(-2.f, rc, 1.f);
                    }
                    if (last) {   // raw state straight to xs (once, exact f32)
                        size_t ob = (size_t)(bbase+ln)*XS_DIM + 5 + nd*64 + w*16 + q*4;
                        #pragma unroll
                        for (int r = 0; r < 4; ++r) xs[ob + r] = th[r];
                    }
                    half2v p0 = pkrtz(th[0], th[1]);
                    half2v p1 = pkrtz(th[2], th[3]);
                    if (nd == 0) {
                        #pragma unroll
                        for (int i = 0; i < NODE; ++i) {
                            gp[i][0] = ahp[i][0]*p0;
                            gp[i][1] = ahp[i][0]*p1;
                        }
                    } else {
                        #pragma unroll
                        for (int i = 0; i < NODE; ++i) {
                            gp[i][0] += ahp[i][nd]*p0;
                            gp[i][1] += ahp[i][nd]*p1;
                        }
                    }
                }
                #pragma unroll
                for (int i = 0; i < NODE; ++i) {
                    h16x4 o;
                    o[0]=gp[i][0][0]; o[1]=gp[i][0][1];
                    o[2]=gp[i][1][0]; o[3]=gp[i][1][1];
                    *(h16x4*)(gsB + gW + i*2048) = o;
                }
            }
            __syncthreads();
        }
    }

    // ---- epilogue: x_end -> xs[b][0..4] ----
    if (tid < NB*NODE) {
        int e = tid / NODE, j = tid - (tid/NODE)*NODE;
        xs[(size_t)(bbase+e)*XS_DIM + j] = (float)sx[1][TB-1][j][e];   // t=511
    }
}

// ---------------------------------------------------------------------------
// Kernel B: h = relu(xs @ fc1_w + fc1_b) + per-column sum/sumsq for BN.
// ---------------------------------------------------------------------------
__global__ __launch_bounds__(256) void fc1_kernel(
    const float* __restrict__ xs, const float* __restrict__ fc1_w,
    const float* __restrict__ fc1_b, float* __restrict__ h,
    float* __restrict__ sums)
{
    __shared__ float s_xs[16*XS_DIM];
    const int tid = threadIdx.x;
    const int r0 = blockIdx.x * 16;
    for (int i = tid; i < 16*XS_DIM; i += 256)
        s_xs[i] = xs[(size_t)r0*XS_DIM + i];
    __syncthreads();

    float acc[16];
    #pragma unroll
    for (int r = 0; r < 16; ++r) acc[r] = 0.f;
    for (int k = 0; k < XS_DIM; ++k) {
        float wv = fc1_w[(size_t)k*H2 + tid];
        #pragma unroll
        for (int r = 0; r < 16; ++r) acc[r] += s_xs[r*XS_DIM + k]*wv;
    }
    float bb = fc1_b[tid];
    float ls = 0.f, lq = 0.f;
    #pragma unroll
    for (int r = 0; r < 16; ++r) {
        float v = fmaxf(acc[r] + bb, 0.f);
        h[(size_t)(r0+r)*H2 + tid] = v;
        ls += v; lq += v*v;
    }
    atomicAdd(&sums[tid], ls);
    atomicAdd(&sums[H2 + tid], lq);
}

// ---------------------------------------------------------------------------
// Kernel C: BN(train) normalize + fc2 + softmax. One wave per row.
// ---------------------------------------------------------------------------
__global__ __launch_bounds__(256) void head_kernel(
    const float* __restrict__ h, const float* __restrict__ sums,
    const float* __restrict__ gamma, const float* __restrict__ beta,
    const float* __restrict__ fc2_w, const float* __restrict__ fc2_b,
    float* __restrict__ out)
{
    const int lane = threadIdx.x & 63;
    const int r = blockIdx.x*4 + (threadIdx.x >> 6);
    const int c0 = lane*4;

    float4 hv = *(const float4*)&h[(size_t)r*H2 + c0];
    float hvv[4] = {hv.x, hv.y, hv.z, hv.w};
    float y[4];
    #pragma unroll
    for (int c = 0; c < 4; ++c) {
        int cc = c0 + c;
        float mean = sums[cc] * (1.f/NBATCH);
        float var  = sums[H2+cc]*(1.f/NBATCH) - mean*mean;
        float rstd = rsqrtf(var + EPS);
        y[c] = (hvv[c] - mean)*rstd*gamma[cc] + beta[cc];
    }
    float lg[7];
    #pragma unroll
    for (int j = 0; j < 7; ++j) {
        float p = 0.f;
        #pragma unroll
        for (int c = 0; c < 4; ++c) p += y[c]*fc2_w[(size_t)(c0+c)*7 + j];
        #pragma unroll
        for (int off = 32; off >= 1; off >>= 1) p += __shfl_xor(p, off, 64);
        lg[j] = p + fc2_b[j];
    }
    if (lane == 0) {
        float m = lg[0];
        #pragma unroll
        for (int j = 1; j < 7; ++j) m = fmaxf(m, lg[j]);
        float ev[7]; float s = 0.f;
        #pragma unroll
        for (int j = 0; j < 7; ++j) { ev[j] = expf(lg[j]-m); s += ev[j]; }
        float inv = 1.f/s;
        #pragma unroll
        for (int j = 0; j < 7; ++j) out[(size_t)r*7 + j] = ev[j]*inv;
    }
}

// ---------------------------------------------------------------------------
extern "C" void kernel_launch(void* const* d_in, const int* in_sizes, int n_in,
                              void* d_out, int out_size, void* d_ws, size_t ws_size,
                              hipStream_t stream)
{
    (void)in_sizes; (void)n_in; (void)out_size; (void)ws_size;
    const float* x     = (const float*)d_in[0];
    const float* adj   = (const float*)d_in[1];
    const float* W0    = (const float*)d_in[2];
    const float* b0    = (const float*)d_in[3];
    const float* W1    = (const float*)d_in[4];
    const float* b1    = (const float*)d_in[5];
    const float* W2    = (const float*)d_in[6];
    const float* b2    = (const float*)d_in[7];
    const float* fc1w  = (const float*)d_in[8];
    const float* fc1b  = (const float*)d_in[9];
    const float* gamma = (const float*)d_in[10];
    const float* beta  = (const float*)d_in[11];
    const float* fc2w  = (const float*)d_in[12];
    const float* fc2b  = (const float*)d_in[13];
    float* out = (float*)d_out;

    char* ws = (char*)d_ws;
    float* xs   = (float*)(ws);                                  // 8192*325 f32
    float* hbuf = (float*)(ws + 10649600);                       // 8192*256 f32
    float* sums = (float*)(ws + 10649600 + 8388608);             // 512 f32

    hipMemsetAsync(sums, 0, 512*sizeof(float), stream);
    rnn_kernel<<<NBATCH/NB, 256, 0, stream>>>(x, adj, W0, b0, W1, b1, W2, b2, xs);
    fc1_kernel<<<NBATCH/16, 256, 0, stream>>>(xs, fc1w, fc1b, hbuf, sums);
    head_kernel<<<NBATCH/4, 256, 0, stream>>>(hbuf, sums, gamma, beta, fc2w, fc2b, out);
}